// Round 4
// baseline (69.636 us; speedup 1.0000x reference)
//
#include <hip/hip_runtime.h>
#include <math.h>

// Problem dims (fixed by setup_inputs)
constexpr int B = 8;
constexpr int A = 49104;
constexpr int C = 80;       // classes
constexpr int M = 32;       // max annotations
constexpr int TILE = 256;   // anchors per block == threads per block
constexpr int NTILES = (A + TILE - 1) / TILE;  // 192

#define F_ALPHA 0.25f

// ws layout (floats): [0..7]=cls_sum, [8..15]=reg_sum, [16..23]=npos
__global__ void init_ws_kernel(float* ws) {
    int t = threadIdx.x;
    if (t < 24) ws[t] = 0.0f;
}

__global__ __launch_bounds__(TILE) void focal_main_kernel(
    const float* __restrict__ cls,      // (B, A, C)
    const float* __restrict__ reg,      // (B, A, 4)
    const float* __restrict__ anchors,  // (A, 4)  y1,x1,y2,x2
    const float* __restrict__ ann,      // (B, M, 5) x1,y1,x2,y2,label
    float* __restrict__ ws)
{
    __shared__ float s_ann[M][5];
    __shared__ int   s_state[TILE];   // >=0: pos with label; -1: neg; -2: ignore
    __shared__ float s_red[3][4];

    const int t    = threadIdx.x;
    const int tile = blockIdx.x;
    const int b    = blockIdx.y;
    const int base = tile * TILE;
    const int nA   = min(TILE, A - base);

    if (t < M * 5) ((float*)s_ann)[t] = ann[b * M * 5 + t];
    __syncthreads();

    float reg_part  = 0.0f;
    float npos_part = 0.0f;
    int state = -2;

    if (t < nA) {
        const int a = base + t;
        const float4 an = ((const float4*)anchors)[a];  // y1,x1,y2,x2
        const float aw  = an.w - an.y;
        const float ah  = an.z - an.x;
        const float acx = an.y + 0.5f * aw;
        const float acy = an.x + 0.5f * ah;
        const float aarea = ah * aw;

        float best = -2.0f;   // below the -1 sentinel
        int   arg  = 0;
        #pragma unroll
        for (int j = 0; j < M; ++j) {
            const float bx1 = s_ann[j][0];
            const float by1 = s_ann[j][1];
            const float bx2 = s_ann[j][2];
            const float by2 = s_ann[j][3];
            const float lb  = s_ann[j][4];
            float iw = fminf(an.w, bx2) - fmaxf(an.y, bx1);
            float ih = fminf(an.z, by2) - fmaxf(an.x, by1);
            iw = fmaxf(iw, 0.0f);
            ih = fmaxf(ih, 0.0f);
            const float inter = iw * ih;
            const float area  = (bx2 - bx1) * (by2 - by1);
            const float ua    = fmaxf(aarea + area - inter, 1e-8f);
            const float iou   = (lb != -1.0f) ? (inter / ua) : -1.0f;
            if (iou > best) { best = iou; arg = j; }   // strict > == argmax first-occurrence
        }
        const bool pos = best >= 0.5f;
        const bool neg = best <  0.4f;
        const int  lab = (int)s_ann[arg][4];
        state = pos ? lab : (neg ? -1 : -2);

        if (pos) {
            npos_part = 1.0f;
            const float4 r = ((const float4*)reg)[(size_t)b * A + a];
            const float ax1 = s_ann[arg][0];
            const float ay1 = s_ann[arg][1];
            const float ax2 = s_ann[arg][2];
            const float ay2 = s_ann[arg][3];
            float gw = ax2 - ax1;
            float gh = ay2 - ay1;
            const float gcx = ax1 + 0.5f * gw;
            const float gcy = ay1 + 0.5f * gh;
            gw = fmaxf(gw, 1.0f);
            gh = fmaxf(gh, 1.0f);
            const float t0 = (gcy - acy) / ah;
            const float t1 = (gcx - acx) / aw;
            const float t2 = __logf(gh / ah);
            const float t3 = __logf(gw / aw);
            const float d0 = fabsf(t0 - r.x);
            const float d1 = fabsf(t1 - r.y);
            const float d2 = fabsf(t2 - r.z);
            const float d3 = fabsf(t3 - r.w);
            const float TH = 1.0f / 9.0f;
            const float SH = 0.5f / 9.0f;
            reg_part = ((d0 <= TH) ? 4.5f * d0 * d0 : d0 - SH)
                     + ((d1 <= TH) ? 4.5f * d1 * d1 : d1 - SH)
                     + ((d2 <= TH) ? 4.5f * d2 * d2 : d2 - SH)
                     + ((d3 <= TH) ? 4.5f * d3 * d3 : d3 - SH);
        }
    }
    s_state[t] = state;
    __syncthreads();

    // Phase B: coalesced focal-BCE sweep over this tile's classification block.
    float cls_part = 0.0f;
    const float4* cp = (const float4*)(cls + ((size_t)b * A + base) * C);
    const int QPA   = C / 4;          // 20 float4 per anchor
    const int nquad = nA * QPA;
    for (int k = t; k < nquad; k += TILE) {
        const int anc = k / QPA;
        const int c0  = (k - anc * QPA) * 4;
        const int st  = s_state[anc];
        if (st == -2) continue;       // ignore band: zero contribution
        const float4 p4 = cp[k];
        const float pv[4] = {p4.x, p4.y, p4.z, p4.w};
        #pragma unroll
        for (int j = 0; j < 4; ++j) {
            const float p = fminf(fmaxf(pv[j], 1e-4f), 1.0f - 1e-4f);
            if (st == c0 + j) {
                const float q = 1.0f - p;
                cls_part += F_ALPHA * q * q * (-__logf(p));
            } else {
                cls_part += (1.0f - F_ALPHA) * p * p * (-__logf(1.0f - p));
            }
        }
    }

    // Block reduction: wave shuffle then cross-wave via LDS.
    for (int off = 32; off > 0; off >>= 1) {
        cls_part  += __shfl_down(cls_part,  off, 64);
        reg_part  += __shfl_down(reg_part,  off, 64);
        npos_part += __shfl_down(npos_part, off, 64);
    }
    const int wave = t >> 6;
    const int lane = t & 63;
    if (lane == 0) {
        s_red[0][wave] = cls_part;
        s_red[1][wave] = reg_part;
        s_red[2][wave] = npos_part;
    }
    __syncthreads();
    if (t == 0) {
        float cs = 0.0f, rs = 0.0f, ns = 0.0f;
        #pragma unroll
        for (int w = 0; w < 4; ++w) {
            cs += s_red[0][w];
            rs += s_red[1][w];
            ns += s_red[2][w];
        }
        atomicAdd(&ws[b],      cs);
        atomicAdd(&ws[8 + b],  rs);
        atomicAdd(&ws[16 + b], ns);
    }
}

__global__ void finalize_kernel(const float* __restrict__ ws,
                                const float* __restrict__ ann,
                                float* __restrict__ out)
{
    const int t = threadIdx.x;  // 64 threads, one wave
    float cls_v = 0.0f, reg_v = 0.0f;
    if (t < B) {
        bool has_valid = false;
        for (int m = 0; m < M; ++m)
            has_valid = has_valid || (ann[t * M * 5 + m * 5 + 4] != -1.0f);
        const float npos = ws[16 + t];
        const float cs = ws[t] / fmaxf(npos, 1.0f);
        cls_v = has_valid ? cs : 0.0f;
        reg_v = (npos > 0.0f) ? (ws[8 + t] / fmaxf(npos * 4.0f, 1.0f)) : 0.0f;
    }
    for (int off = 32; off > 0; off >>= 1) {
        cls_v += __shfl_down(cls_v, off, 64);
        reg_v += __shfl_down(reg_v, off, 64);
    }
    if (t == 0) {
        out[0] = cls_v * (1.0f / (float)B);
        out[1] = reg_v * (1.0f / (float)B);
    }
}

extern "C" void kernel_launch(void* const* d_in, const int* in_sizes, int n_in,
                              void* d_out, int out_size, void* d_ws, size_t ws_size,
                              hipStream_t stream) {
    const float* cls     = (const float*)d_in[0];
    const float* reg     = (const float*)d_in[1];
    const float* anchors = (const float*)d_in[2];
    const float* ann     = (const float*)d_in[3];
    float* out = (float*)d_out;
    float* ws  = (float*)d_ws;

    init_ws_kernel<<<1, 32, 0, stream>>>(ws);
    focal_main_kernel<<<dim3(NTILES, B), TILE, 0, stream>>>(cls, reg, anchors, ann, ws);
    finalize_kernel<<<1, 64, 0, stream>>>(ws, ann, out);
}

// Round 5
// 62.820 us; speedup vs baseline: 1.1085x; 1.1085x over previous
//
#include <hip/hip_runtime.h>
#include <math.h>

// Problem dims (fixed by setup_inputs)
constexpr int B = 8;
constexpr int A = 49104;
constexpr int C = 80;       // classes
constexpr int M = 32;       // max annotations
constexpr int TILE = 256;   // anchors per block == threads per block
constexpr int NTILES = (A + TILE - 1) / TILE;  // 192

// ws layout (floats): [0..7]=cls_sum (log2 units), [8..15]=reg_sum, [16..23]=npos
__global__ void init_ws_kernel(float* ws) {
    int t = threadIdx.x;
    if (t < 24) ws[t] = 0.0f;
}

__global__ __launch_bounds__(TILE) void focal_main_kernel(
    const float* __restrict__ cls,      // (B, A, C)
    const float* __restrict__ reg,      // (B, A, 4)
    const float* __restrict__ anchors,  // (A, 4)  y1,x1,y2,x2
    const float* __restrict__ ann,      // (B, M, 5) x1,y1,x2,y2,label
    float* __restrict__ ws)
{
    __shared__ float s_ann[M][5];
    __shared__ float s_w[TILE];       // 0.75 for pos|neg anchors, 0 for ignore/tail
    __shared__ float s_red[3][4];

    const int t    = threadIdx.x;
    const int tile = blockIdx.x;
    const int b    = blockIdx.y;
    const int base = tile * TILE;
    const int nA   = min(TILE, A - base);

    if (t < M * 5) ((float*)s_ann)[t] = ann[b * M * 5 + t];
    __syncthreads();

    float cls_part  = 0.0f;   // log2 units
    float reg_part  = 0.0f;
    float npos_part = 0.0f;
    float w = 0.0f;

    if (t < nA) {
        const int a = base + t;
        const float4 an = ((const float4*)anchors)[a];  // y1,x1,y2,x2
        const float aw  = an.w - an.y;
        const float ah  = an.z - an.x;
        const float acx = an.y + 0.5f * aw;
        const float acy = an.x + 0.5f * ah;
        const float aarea = ah * aw;

        float best = -2.0f;   // below the -1 sentinel
        int   arg  = 0;
        #pragma unroll
        for (int j = 0; j < M; ++j) {
            const float bx1 = s_ann[j][0];
            const float by1 = s_ann[j][1];
            const float bx2 = s_ann[j][2];
            const float by2 = s_ann[j][3];
            const float lb  = s_ann[j][4];
            float iw = fminf(an.w, bx2) - fmaxf(an.y, bx1);
            float ih = fminf(an.z, by2) - fmaxf(an.x, by1);
            iw = fmaxf(iw, 0.0f);
            ih = fmaxf(ih, 0.0f);
            const float inter = iw * ih;
            const float area  = (bx2 - bx1) * (by2 - by1);
            const float ua    = fmaxf(aarea + area - inter, 1e-8f);
            const float iou   = (lb != -1.0f) ? (inter / ua) : -1.0f;
            if (iou > best) { best = iou; arg = j; }   // strict > == argmax first-occurrence
        }
        const bool pos = best >= 0.5f;
        const bool neg = best <  0.4f;
        w = (pos || neg) ? 0.75f : 0.0f;

        if (pos) {
            npos_part = 1.0f;
            const int lab = (int)s_ann[arg][4];
            // --- cls correction for the label element (then-term minus the
            // else-term Phase B will blindly add). All in log2 units.
            const float pl = fminf(fmaxf(cls[((size_t)b * A + a) * C + lab], 1e-4f), 1.0f - 1e-4f);
            const float ql = 1.0f - pl;
            cls_part = -0.25f * ql * ql * __log2f(pl) + 0.75f * pl * pl * __log2f(ql);

            // --- smooth-L1 regression term (unchanged, natural-log units)
            const float4 r = ((const float4*)reg)[(size_t)b * A + a];
            const float ax1 = s_ann[arg][0];
            const float ay1 = s_ann[arg][1];
            const float ax2 = s_ann[arg][2];
            const float ay2 = s_ann[arg][3];
            float gw = ax2 - ax1;
            float gh = ay2 - ay1;
            const float gcx = ax1 + 0.5f * gw;
            const float gcy = ay1 + 0.5f * gh;
            gw = fmaxf(gw, 1.0f);
            gh = fmaxf(gh, 1.0f);
            const float t0 = (gcy - acy) / ah;
            const float t1 = (gcx - acx) / aw;
            const float t2 = __logf(gh / ah);
            const float t3 = __logf(gw / aw);
            const float d0 = fabsf(t0 - r.x);
            const float d1 = fabsf(t1 - r.y);
            const float d2 = fabsf(t2 - r.z);
            const float d3 = fabsf(t3 - r.w);
            const float TH = 1.0f / 9.0f;
            const float SH = 0.5f / 9.0f;
            reg_part = ((d0 <= TH) ? 4.5f * d0 * d0 : d0 - SH)
                     + ((d1 <= TH) ? 4.5f * d1 * d1 : d1 - SH)
                     + ((d2 <= TH) ? 4.5f * d2 * d2 : d2 - SH)
                     + ((d3 <= TH) ? 4.5f * d3 * d3 : d3 - SH);
        }
    }
    s_w[t] = w;
    __syncthreads();

    // Phase B: branchless focal-BCE "else-branch" stream over the tile's
    // 256x80 cls block. loss_elem = w * p^2 * (-log2(1-p)); pos-label fixup
    // was already applied in Phase A.
    const float4* cp = (const float4*)(cls + ((size_t)b * A + base) * C);
    const int nquad = nA * (C / 4);   // 20 float4 per anchor
    #pragma unroll 2
    for (int k = t; k < nquad; k += TILE) {
        const int anc = (int)((unsigned)k / 20u);
        const float wq = s_w[anc];
        const float4 p4 = cp[k];
        {
            const float p = fminf(fmaxf(p4.x, 1e-4f), 1.0f - 1e-4f);
            cls_part = fmaf(-wq, p * p * __log2f(1.0f - p), cls_part);
        }
        {
            const float p = fminf(fmaxf(p4.y, 1e-4f), 1.0f - 1e-4f);
            cls_part = fmaf(-wq, p * p * __log2f(1.0f - p), cls_part);
        }
        {
            const float p = fminf(fmaxf(p4.z, 1e-4f), 1.0f - 1e-4f);
            cls_part = fmaf(-wq, p * p * __log2f(1.0f - p), cls_part);
        }
        {
            const float p = fminf(fmaxf(p4.w, 1e-4f), 1.0f - 1e-4f);
            cls_part = fmaf(-wq, p * p * __log2f(1.0f - p), cls_part);
        }
    }

    // Block reduction: wave shuffle then cross-wave via LDS.
    for (int off = 32; off > 0; off >>= 1) {
        cls_part  += __shfl_down(cls_part,  off, 64);
        reg_part  += __shfl_down(reg_part,  off, 64);
        npos_part += __shfl_down(npos_part, off, 64);
    }
    const int wave = t >> 6;
    const int lane = t & 63;
    if (lane == 0) {
        s_red[0][wave] = cls_part;
        s_red[1][wave] = reg_part;
        s_red[2][wave] = npos_part;
    }
    __syncthreads();
    if (t == 0) {
        float cs = 0.0f, rs = 0.0f, ns = 0.0f;
        #pragma unroll
        for (int wv = 0; wv < 4; ++wv) {
            cs += s_red[0][wv];
            rs += s_red[1][wv];
            ns += s_red[2][wv];
        }
        atomicAdd(&ws[b],      cs);
        atomicAdd(&ws[8 + b],  rs);
        atomicAdd(&ws[16 + b], ns);
    }
}

__global__ void finalize_kernel(const float* __restrict__ ws,
                                const float* __restrict__ ann,
                                float* __restrict__ out)
{
    const int t = threadIdx.x;  // 64 threads, one wave
    float cls_v = 0.0f, reg_v = 0.0f;
    if (t < B) {
        bool has_valid = false;
        for (int m = 0; m < M; ++m)
            has_valid = has_valid || (ann[t * M * 5 + m * 5 + 4] != -1.0f);
        const float npos = ws[16 + t];
        // cls accumulator is in log2 units -> scale by ln(2)
        const float cs = 0.69314718056f * ws[t] / fmaxf(npos, 1.0f);
        cls_v = has_valid ? cs : 0.0f;
        reg_v = (npos > 0.0f) ? (ws[8 + t] / fmaxf(npos * 4.0f, 1.0f)) : 0.0f;
    }
    for (int off = 32; off > 0; off >>= 1) {
        cls_v += __shfl_down(cls_v, off, 64);
        reg_v += __shfl_down(reg_v, off, 64);
    }
    if (t == 0) {
        out[0] = cls_v * (1.0f / (float)B);
        out[1] = reg_v * (1.0f / (float)B);
    }
}

extern "C" void kernel_launch(void* const* d_in, const int* in_sizes, int n_in,
                              void* d_out, int out_size, void* d_ws, size_t ws_size,
                              hipStream_t stream) {
    const float* cls     = (const float*)d_in[0];
    const float* reg     = (const float*)d_in[1];
    const float* anchors = (const float*)d_in[2];
    const float* ann     = (const float*)d_in[3];
    float* out = (float*)d_out;
    float* ws  = (float*)d_ws;

    init_ws_kernel<<<1, 32, 0, stream>>>(ws);
    focal_main_kernel<<<dim3(NTILES, B), TILE, 0, stream>>>(cls, reg, anchors, ann, ws);
    finalize_kernel<<<1, 64, 0, stream>>>(ws, ann, out);
}

// Round 8
// 62.207 us; speedup vs baseline: 1.1194x; 1.0099x over previous
//
#include <hip/hip_runtime.h>
#include <math.h>

// Problem dims (fixed by setup_inputs)
constexpr int B = 8;
constexpr int A = 49104;
constexpr int C = 80;       // classes
constexpr int M = 32;       // max annotations
constexpr int TILE = 256;   // anchors per block == threads per block
constexpr int NTILES = (A + TILE - 1) / TILE;  // 192

// ws layout (floats): [0..7]=cls_sum (log2 units), [8..15]=reg_sum, [16..23]=npos
__global__ void init_ws_kernel(float* ws) {
    int t = threadIdx.x;
    if (t < 24) ws[t] = 0.0f;
}

__device__ __forceinline__ void focal_quad(const float4 p4, const float wq,
                                           float& accA, float& accB) {
    const float px = fminf(fmaxf(p4.x, 1e-4f), 1.0f - 1e-4f);
    const float py = fminf(fmaxf(p4.y, 1e-4f), 1.0f - 1e-4f);
    const float pz = fminf(fmaxf(p4.z, 1e-4f), 1.0f - 1e-4f);
    const float pw = fminf(fmaxf(p4.w, 1e-4f), 1.0f - 1e-4f);
    accA = fmaf(-wq, px * px * __log2f(1.0f - px), accA);
    accB = fmaf(-wq, py * py * __log2f(1.0f - py), accB);
    accA = fmaf(-wq, pz * pz * __log2f(1.0f - pz), accA);
    accB = fmaf(-wq, pw * pw * __log2f(1.0f - pw), accB);
}

__global__ __launch_bounds__(TILE, 8) void focal_main_kernel(
    const float* __restrict__ cls,      // (B, A, C)
    const float* __restrict__ reg,      // (B, A, 4)
    const float* __restrict__ anchors,  // (A, 4)  y1,x1,y2,x2
    const float* __restrict__ ann,      // (B, M, 5) x1,y1,x2,y2,label
    float* __restrict__ ws)
{
    __shared__ float s_ann[M][5];
    __shared__ float s_w[TILE];       // 0.75 for pos|neg anchors, 0 for ignore/tail
    __shared__ float s_red[3][4];

    const int t    = threadIdx.x;
    const int tile = blockIdx.x;
    const int b    = blockIdx.y;
    const int base = tile * TILE;
    const int nA   = min(TILE, A - base);

    if (t < M * 5) ((float*)s_ann)[t] = ann[b * M * 5 + t];
    __syncthreads();

    float cls_part  = 0.0f;   // log2 units
    float reg_part  = 0.0f;
    float npos_part = 0.0f;
    float w = 0.0f;

    if (t < nA) {
        const int a = base + t;
        const float4 an = ((const float4*)anchors)[a];  // y1,x1,y2,x2
        const float aw  = an.w - an.y;
        const float ah  = an.z - an.x;
        const float acx = an.y + 0.5f * aw;
        const float acy = an.x + 0.5f * ah;
        const float aarea = ah * aw;

        float best = -2.0f;   // below the -1 sentinel
        int   arg  = 0;
        #pragma unroll
        for (int j = 0; j < M; ++j) {
            const float bx1 = s_ann[j][0];
            const float by1 = s_ann[j][1];
            const float bx2 = s_ann[j][2];
            const float by2 = s_ann[j][3];
            const float lb  = s_ann[j][4];
            float iw = fminf(an.w, bx2) - fmaxf(an.y, bx1);
            float ih = fminf(an.z, by2) - fmaxf(an.x, by1);
            iw = fmaxf(iw, 0.0f);
            ih = fmaxf(ih, 0.0f);
            const float inter = iw * ih;
            const float area  = (bx2 - bx1) * (by2 - by1);
            const float ua    = fmaxf(aarea + area - inter, 1e-8f);
            const float iou   = (lb != -1.0f) ? (inter / ua) : -1.0f;
            if (iou > best) { best = iou; arg = j; }   // strict > == argmax first-occurrence
        }
        const bool pos = best >= 0.5f;
        const bool neg = best <  0.4f;
        w = (pos || neg) ? 0.75f : 0.0f;

        if (pos) {
            npos_part = 1.0f;
            const int lab = (int)s_ann[arg][4];
            // cls correction for the label element (then-term minus the
            // else-term Phase B will blindly add). All in log2 units.
            const float pl = fminf(fmaxf(cls[((size_t)b * A + a) * C + lab], 1e-4f), 1.0f - 1e-4f);
            const float ql = 1.0f - pl;
            cls_part = -0.25f * ql * ql * __log2f(pl) + 0.75f * pl * pl * __log2f(ql);

            // smooth-L1 regression term (natural-log units)
            const float4 r = ((const float4*)reg)[(size_t)b * A + a];
            const float ax1 = s_ann[arg][0];
            const float ay1 = s_ann[arg][1];
            const float ax2 = s_ann[arg][2];
            const float ay2 = s_ann[arg][3];
            float gw = ax2 - ax1;
            float gh = ay2 - ay1;
            const float gcx = ax1 + 0.5f * gw;
            const float gcy = ay1 + 0.5f * gh;
            gw = fmaxf(gw, 1.0f);
            gh = fmaxf(gh, 1.0f);
            const float t0 = (gcy - acy) / ah;
            const float t1 = (gcx - acx) / aw;
            const float t2 = __logf(gh / ah);
            const float t3 = __logf(gw / aw);
            const float d0 = fabsf(t0 - r.x);
            const float d1 = fabsf(t1 - r.y);
            const float d2 = fabsf(t2 - r.z);
            const float d3 = fabsf(t3 - r.w);
            const float TH = 1.0f / 9.0f;
            const float SH = 0.5f / 9.0f;
            reg_part = ((d0 <= TH) ? 4.5f * d0 * d0 : d0 - SH)
                     + ((d1 <= TH) ? 4.5f * d1 * d1 : d1 - SH)
                     + ((d2 <= TH) ? 4.5f * d2 * d2 : d2 - SH)
                     + ((d3 <= TH) ? 4.5f * d3 * d3 : d3 - SH);
        }
    }
    s_w[t] = w;
    __syncthreads();

    // Phase B: branchless focal-BCE "else-branch" stream, batched 5 deep for
    // memory-level parallelism (R5 counters: 2-deep MLP sustained only
    // 1.7 TB/s effective; latency-bound, not BW-bound).
    const float4* cp = (const float4*)(cls + ((size_t)b * A + base) * C);
    const int nquad = nA * (C / 4);   // 20 float4 per anchor (full tile: 20/thread)
    float accA = cls_part, accB = 0.0f;

    int k = t;
    for (; k + 4 * TILE < nquad; k += 5 * TILE) {
        // issue 5 independent loads (+ their LDS weight reads) back-to-back
        const float4 q0 = cp[k];
        const float4 q1 = cp[k +     TILE];
        const float4 q2 = cp[k + 2 * TILE];
        const float4 q3 = cp[k + 3 * TILE];
        const float4 q4 = cp[k + 4 * TILE];
        const float w0 = s_w[(unsigned)(k)            / 20u];
        const float w1 = s_w[(unsigned)(k +     TILE) / 20u];
        const float w2 = s_w[(unsigned)(k + 2 * TILE) / 20u];
        const float w3 = s_w[(unsigned)(k + 3 * TILE) / 20u];
        const float w4 = s_w[(unsigned)(k + 4 * TILE) / 20u];
        focal_quad(q0, w0, accA, accB);
        focal_quad(q1, w1, accA, accB);
        focal_quad(q2, w2, accA, accB);
        focal_quad(q3, w3, accA, accB);
        focal_quad(q4, w4, accA, accB);
    }
    for (; k < nquad; k += TILE) {
        const float4 q = cp[k];
        const float wq = s_w[(unsigned)k / 20u];
        focal_quad(q, wq, accA, accB);
    }
    cls_part = accA + accB;

    // Block reduction: wave shuffle then cross-wave via LDS.
    for (int off = 32; off > 0; off >>= 1) {
        cls_part  += __shfl_down(cls_part,  off, 64);
        reg_part  += __shfl_down(reg_part,  off, 64);
        npos_part += __shfl_down(npos_part, off, 64);
    }
    const int wave = t >> 6;
    const int lane = t & 63;
    if (lane == 0) {
        s_red[0][wave] = cls_part;
        s_red[1][wave] = reg_part;
        s_red[2][wave] = npos_part;
    }
    __syncthreads();
    if (t == 0) {
        float cs = 0.0f, rs = 0.0f, ns = 0.0f;
        #pragma unroll
        for (int wv = 0; wv < 4; ++wv) {
            cs += s_red[0][wv];
            rs += s_red[1][wv];
            ns += s_red[2][wv];
        }
        atomicAdd(&ws[b],      cs);
        atomicAdd(&ws[8 + b],  rs);
        atomicAdd(&ws[16 + b], ns);
    }
}

__global__ void finalize_kernel(const float* __restrict__ ws,
                                const float* __restrict__ ann,
                                float* __restrict__ out)
{
    const int t = threadIdx.x;  // 64 threads, one wave
    float cls_v = 0.0f, reg_v = 0.0f;
    if (t < B) {
        bool has_valid = false;
        for (int m = 0; m < M; ++m)
            has_valid = has_valid || (ann[t * M * 5 + m * 5 + 4] != -1.0f);
        const float npos = ws[16 + t];
        // cls accumulator is in log2 units -> scale by ln(2)
        const float cs = 0.69314718056f * ws[t] / fmaxf(npos, 1.0f);
        cls_v = has_valid ? cs : 0.0f;
        reg_v = (npos > 0.0f) ? (ws[8 + t] / fmaxf(npos * 4.0f, 1.0f)) : 0.0f;
    }
    for (int off = 32; off > 0; off >>= 1) {
        cls_v += __shfl_down(cls_v, off, 64);
        reg_v += __shfl_down(reg_v, off, 64);
    }
    if (t == 0) {
        out[0] = cls_v * (1.0f / (float)B);
        out[1] = reg_v * (1.0f / (float)B);
    }
}

extern "C" void kernel_launch(void* const* d_in, const int* in_sizes, int n_in,
                              void* d_out, int out_size, void* d_ws, size_t ws_size,
                              hipStream_t stream) {
    const float* cls     = (const float*)d_in[0];
    const float* reg     = (const float*)d_in[1];
    const float* anchors = (const float*)d_in[2];
    const float* ann     = (const float*)d_in[3];
    float* out = (float*)d_out;
    float* ws  = (float*)d_ws;

    init_ws_kernel<<<1, 32, 0, stream>>>(ws);
    focal_main_kernel<<<dim3(NTILES, B), TILE, 0, stream>>>(cls, reg, anchors, ann, ws);
    finalize_kernel<<<1, 64, 0, stream>>>(ws, ann, out);
}